// Round 2
// baseline (2348.429 us; speedup 1.0000x reference)
//
#include <hip/hip_runtime.h>
#include <hip/hip_bf16.h>

// trackletGNN: 3x edge-conv (gather * edge-linear -> scatter-add) + MLP head.
// Strategy: counting-sort edges by dst ONCE (int atomics only), then each conv
// layer is an atomic-free per-node segmented reduction with L3-resident gather
// tables. Wo+ReLU+next-layer-Wx fused into the aggregation epilogue.
//
// Float dtype (f32 vs bf16) is detected AT RUNTIME by k_detect: reading f32
// data as bf16 exposes mantissa-garbage halves (|v|>1e3 or NaN with ~46%/sample).
// All kernels branch wave-uniformly on the flag. Internal node-feature tables
// are always bf16 (rounding error ~0.2% << 2% threshold).
// Workspace usage: ~180 MB.

#define NNODES 1500000
#define NEDGES 12000000
#define NTRACK 250000
#define HSTR   12          // padded bf16 feature stride (9 used) -> 24B
#define EPB    4096        // elements per scan block
#define NBLK   367         // ceil(NNODES/EPB)

typedef unsigned int   u32;
typedef unsigned short u16;

static __device__ __forceinline__ float b2f(u32 v) {
    union { float f; u32 u; } x; x.u = v << 16; return x.f;
}
static __device__ __forceinline__ u16 f2b(float f) {
    __hip_bfloat16 h = __float2bfloat16(f);
    return *reinterpret_cast<u16*>(&h);
}
// load weight element i from buffer that is either f32 or bf16
static __device__ __forceinline__ float ldw(const void* p, int i, int isf32) {
    return isf32 ? ((const float*)p)[i] : b2f((u32)((const u16*)p)[i]);
}

// ---------------- dtype probe ----------------

__global__ void k_detect(const u16* a, const u16* b, const u16* c,
                         const u16* d, const u16* e, const u16* f,
                         int* flag) {
    if (blockIdx.x == 0 && threadIdx.x == 0) {
        int isf32 = 0;
        const u16* ps[6] = {a, b, c, d, e, f};
        const int  ns[6] = {9, 9, 9, 9, 9, 8};
        for (int k = 0; k < 6; k++)
            for (int i = 0; i < ns[k]; i++) {
                float v = b2f((u32)ps[k][i]);
                if (!(fabsf(v) < 1.0e3f)) isf32 = 1;   // catches NaN/Inf too
            }
        *flag = isf32;
    }
}

// ---------------- sort-by-dst machinery ----------------

__global__ __launch_bounds__(256) void k_hist(const int* __restrict__ dst,
                                              int* __restrict__ cnt) {
    int e = blockIdx.x * 256 + threadIdx.x;
    if (e < NEDGES) atomicAdd(&cnt[dst[e]], 1);
}

__global__ __launch_bounds__(256) void k_reduce(const int* __restrict__ cnt,
                                                int* __restrict__ part) {
    __shared__ int sd[256];
    int t = threadIdx.x;
    int base = blockIdx.x * EPB;
    int s = 0;
#pragma unroll
    for (int k = 0; k < 16; k++) {
        int i = base + t * 16 + k;
        if (i < NNODES) s += cnt[i];
    }
    sd[t] = s; __syncthreads();
    for (int o = 128; o > 0; o >>= 1) {
        if (t < o) sd[t] += sd[t + o];
        __syncthreads();
    }
    if (t == 0) part[blockIdx.x] = sd[0];
}

__global__ __launch_bounds__(512) void k_scanpart(int* __restrict__ part,
                                                  int* __restrict__ row_start) {
    __shared__ int sd[512];
    int t = threadIdx.x;
    int v = (t < NBLK) ? part[t] : 0;
    sd[t] = v; __syncthreads();
    for (int o = 1; o < 512; o <<= 1) {
        int add = (t >= o) ? sd[t - o] : 0;
        __syncthreads();
        sd[t] += add;
        __syncthreads();
    }
    if (t < NBLK) part[t] = sd[t] - v;   // exclusive scan in place
    if (t == 0) row_start[NNODES] = NEDGES;
}

__global__ __launch_bounds__(256) void k_scandown(int* __restrict__ arr,
                                                  const int* __restrict__ part,
                                                  int* __restrict__ cursor) {
    __shared__ int sd[256];
    int t = threadIdx.x;
    int base = blockIdx.x * EPB;
    int c[16];
    int s = 0;
#pragma unroll
    for (int k = 0; k < 16; k++) {
        int i = base + t * 16 + k;
        c[k] = (i < NNODES) ? arr[i] : 0;
        s += c[k];
    }
    sd[t] = s; __syncthreads();
    for (int o = 1; o < 256; o <<= 1) {
        int add = (t >= o) ? sd[t - o] : 0;
        __syncthreads();
        sd[t] += add;
        __syncthreads();
    }
    int run = part[blockIdx.x] + sd[t] - s;  // exclusive prefix for this thread
#pragma unroll
    for (int k = 0; k < 16; k++) {
        int i = base + t * 16 + k;
        if (i < NNODES) { arr[i] = run; cursor[i] = run; }
        run += c[k];
    }
}

__global__ __launch_bounds__(256) void k_scatter(const int* __restrict__ src,
                                                 const int* __restrict__ dst,
                                                 const void* __restrict__ attr,
                                                 int* __restrict__ cursor,
                                                 uint2* __restrict__ perm,
                                                 const int* __restrict__ flag) {
    int isf32 = *flag;
    int e = blockIdx.x * 256 + threadIdx.x;
    if (e < NEDGES) {
        int d = dst[e];
        int p = atomicAdd(&cursor[d], 1);
        u32 packed;
        if (isf32) {
            float2 a = ((const float2*)attr)[e];
            packed = (u32)f2b(a.x) | ((u32)f2b(a.y) << 16);
        } else {
            packed = ((const u32*)attr)[e];
        }
        uint2 rec; rec.x = (u32)src[e]; rec.y = packed;
        perm[p] = rec;
    }
}

// ---- layer 1: gather scalar x, fuse Wx1 + edge-linear + Wo1 + ReLU + Wx2 ----

__global__ __launch_bounds__(256) void k_agg1(
        const int* __restrict__ row_start, const uint2* __restrict__ perm,
        const void* __restrict__ x,
        const void* Wx, const void* bx, const void* We, const void* be,
        const void* Wo, const void* bo, const void* Wxn, const void* bxn,
        u16* __restrict__ hout, const int* __restrict__ flag) {
    __shared__ float sWx[9], sbx[9], sWe[18], sbe[9], sWo[81], sbo[9], sWxn[81], sbxn[9];
    int isf32 = *flag;
    int t = threadIdx.x;
    if (t < 9)  sWx[t]  = ldw(Wx,  t, isf32);
    if (t < 9)  sbx[t]  = ldw(bx,  t, isf32);
    if (t < 18) sWe[t]  = ldw(We,  t, isf32);
    if (t < 9)  sbe[t]  = ldw(be,  t, isf32);
    if (t < 81) sWo[t]  = ldw(Wo,  t, isf32);
    if (t < 9)  sbo[t]  = ldw(bo,  t, isf32);
    if (t < 81) sWxn[t] = ldw(Wxn, t, isf32);
    if (t < 9)  sbxn[t] = ldw(bxn, t, isf32);
    __syncthreads();

    int n = blockIdx.x * 256 + t;
    if (n >= NNODES) return;
    int r0 = row_start[n], r1 = row_start[n + 1];

    float acc[9];
#pragma unroll
    for (int j = 0; j < 9; j++) acc[j] = 0.f;

    auto body = [&](float xs, u32 ap) {
        float a0 = b2f(ap & 0xffffu);
        float a1 = b2f(ap >> 16);
#pragma unroll
        for (int j = 0; j < 9; j++) {
            float e = fmaf(a0, sWe[2 * j], fmaf(a1, sWe[2 * j + 1], sbe[j]));
            float h = fmaf(xs, sWx[j], sbx[j]);
            acc[j]  = fmaf(h, e, acc[j]);
        }
    };
    if (isf32) {
        const float* xf = (const float*)x;
        for (int i = r0; i < r1; i++) {
            uint2 rec = perm[i];
            body(xf[(int)rec.x], rec.y);
        }
    } else {
        const u16* xb = (const u16*)x;
        for (int i = r0; i < r1; i++) {
            uint2 rec = perm[i];
            body(b2f((u32)xb[(int)rec.x]), rec.y);
        }
    }

    float o[9];
#pragma unroll
    for (int k = 0; k < 9; k++) {
        float v = sbo[k];
#pragma unroll
        for (int j = 0; j < 9; j++) v = fmaf(acc[j], sWo[k * 9 + j], v);
        o[k] = fmaxf(v, 0.f);
    }
    u16 hv[9];
#pragma unroll
    for (int j = 0; j < 9; j++) {
        float v = sbxn[j];
#pragma unroll
        for (int k = 0; k < 9; k++) v = fmaf(o[k], sWxn[j * 9 + k], v);
        hv[j] = f2b(v);
    }
    uint2* op = (uint2*)(hout + (size_t)n * HSTR);
    uint2 q;
    q.x = (u32)hv[0] | ((u32)hv[1] << 16); q.y = (u32)hv[2] | ((u32)hv[3] << 16); op[0] = q;
    q.x = (u32)hv[4] | ((u32)hv[5] << 16); q.y = (u32)hv[6] | ((u32)hv[7] << 16); op[1] = q;
    q.x = (u32)hv[8];                      q.y = 0;                               op[2] = q;
}

// ---------------- layers 2/3: gather 9-vec from bf16 table ----------------

template <int OUTF, bool FUSE_NEXT>
__global__ __launch_bounds__(256) void k_agg(
        const int* __restrict__ row_start, const uint2* __restrict__ perm,
        const u16* __restrict__ hcur,
        const void* We, const void* be, const void* Wo, const void* bo,
        const void* Wxn, const void* bxn,
        u16* __restrict__ hout, const int* __restrict__ flag) {
    __shared__ float sWe[18], sbe[9], sWo[OUTF * 9], sbo[OUTF], sWxn[81], sbxn[9];
    int isf32 = *flag;
    int t = threadIdx.x;
    if (t < 18)       sWe[t] = ldw(We, t, isf32);
    if (t < 9)        sbe[t] = ldw(be, t, isf32);
    if (t < OUTF * 9) sWo[t] = ldw(Wo, t, isf32);
    if (t < OUTF)     sbo[t] = ldw(bo, t, isf32);
    if constexpr (FUSE_NEXT) {
        if (t < 81) sWxn[t] = ldw(Wxn, t, isf32);
        if (t < 9)  sbxn[t] = ldw(bxn, t, isf32);
    }
    __syncthreads();

    int n = blockIdx.x * 256 + t;
    if (n >= NNODES) return;
    int r0 = row_start[n], r1 = row_start[n + 1];

    float acc[9];
#pragma unroll
    for (int j = 0; j < 9; j++) acc[j] = 0.f;

    for (int i = r0; i < r1; i++) {
        uint2 rec = perm[i];
        int   s   = (int)rec.x;
        float a0  = b2f(rec.y & 0xffffu);
        float a1  = b2f(rec.y >> 16);
        const uint2* hp = (const uint2*)(hcur + (size_t)s * HSTR);
        uint2 q0 = hp[0], q1 = hp[1], q2 = hp[2];
        float h[9];
        h[0] = b2f(q0.x & 0xffffu); h[1] = b2f(q0.x >> 16);
        h[2] = b2f(q0.y & 0xffffu); h[3] = b2f(q0.y >> 16);
        h[4] = b2f(q1.x & 0xffffu); h[5] = b2f(q1.x >> 16);
        h[6] = b2f(q1.y & 0xffffu); h[7] = b2f(q1.y >> 16);
        h[8] = b2f(q2.x & 0xffffu);
#pragma unroll
        for (int j = 0; j < 9; j++) {
            float e = fmaf(a0, sWe[2 * j], fmaf(a1, sWe[2 * j + 1], sbe[j]));
            acc[j]  = fmaf(h[j], e, acc[j]);
        }
    }

    float o[OUTF];
#pragma unroll
    for (int k = 0; k < OUTF; k++) {
        float v = sbo[k];
#pragma unroll
        for (int j = 0; j < 9; j++) v = fmaf(acc[j], sWo[k * 9 + j], v);
        o[k] = fmaxf(v, 0.f);
    }

    if constexpr (FUSE_NEXT) {
        u16 hv[9];
#pragma unroll
        for (int j = 0; j < 9; j++) {
            float v = sbxn[j];
#pragma unroll
            for (int k = 0; k < OUTF; k++) v = fmaf(o[k], sWxn[j * 9 + k], v);
            hv[j] = f2b(v);
        }
        uint2* op = (uint2*)(hout + (size_t)n * HSTR);
        uint2 q;
        q.x = (u32)hv[0] | ((u32)hv[1] << 16); q.y = (u32)hv[2] | ((u32)hv[3] << 16); op[0] = q;
        q.x = (u32)hv[4] | ((u32)hv[5] << 16); q.y = (u32)hv[6] | ((u32)hv[7] << 16); op[1] = q;
        q.x = (u32)hv[8];                      q.y = 0;                               op[2] = q;
    } else {
        uint2 q;
        q.x = (u32)f2b(o[0]) | ((u32)f2b(o[1]) << 16);
        q.y = (u32)f2b(o[2]) | ((u32)f2b(o[3]) << 16);
        ((uint2*)(hout + (size_t)n * 4))[0] = q;
    }
}

// ---------------- head MLP + log_softmax ----------------

__global__ __launch_bounds__(256) void k_head(
        const u16* __restrict__ f,
        const void* W1, const void* b1, const void* W2, const void* b2,
        void* __restrict__ out, const int* __restrict__ flag) {
    __shared__ float sW1[192], sb1[8], sW2[32], sb2[4];
    int isf32 = *flag;
    int t = threadIdx.x;
    if (t < 192) sW1[t] = ldw(W1, t, isf32);
    if (t < 8)   sb1[t] = ldw(b1, t, isf32);
    if (t < 32)  sW2[t] = ldw(W2, t, isf32);
    if (t < 4)   sb2[t] = ldw(b2, t, isf32);
    __syncthreads();

    int tr = blockIdx.x * 256 + t;
    if (tr >= NTRACK) return;

    const uint4* fp = (const uint4*)(f + (size_t)tr * 24);  // 48B, 16B-aligned
    uint4 A = fp[0], B = fp[1], C = fp[2];
    u32 w[12] = {A.x, A.y, A.z, A.w, B.x, B.y, B.z, B.w, C.x, C.y, C.z, C.w};
    float in[24];
#pragma unroll
    for (int i = 0; i < 12; i++) {
        in[2 * i]     = b2f(w[i] & 0xffffu);
        in[2 * i + 1] = b2f(w[i] >> 16);
    }

    float z1[8];
#pragma unroll
    for (int o = 0; o < 8; o++) {
        float v = sb1[o];
#pragma unroll
        for (int i = 0; i < 24; i++) v = fmaf(in[i], sW1[o * 24 + i], v);
        z1[o] = fmaxf(v, 0.f);
    }
    float z2[4];
#pragma unroll
    for (int c = 0; c < 4; c++) {
        float v = sb2[c];
#pragma unroll
        for (int o = 0; o < 8; o++) v = fmaf(z1[o], sW2[c * 8 + o], v);
        z2[c] = v;
    }
    float m = fmaxf(fmaxf(z2[0], z2[1]), fmaxf(z2[2], z2[3]));
    float s = 0.f;
#pragma unroll
    for (int c = 0; c < 4; c++) s += expf(z2[c] - m);
    float l = logf(s) + m;

    if (isf32) {
        float4 q; q.x = z2[0] - l; q.y = z2[1] - l; q.z = z2[2] - l; q.w = z2[3] - l;
        ((float4*)((float*)out + (size_t)tr * 4))[0] = q;
    } else {
        uint2 q;
        q.x = (u32)f2b(z2[0] - l) | ((u32)f2b(z2[1] - l) << 16);
        q.y = (u32)f2b(z2[2] - l) | ((u32)f2b(z2[3] - l) << 16);
        ((uint2*)((u16*)out + (size_t)tr * 4))[0] = q;
    }
}

// ---------------- host ----------------

extern "C" void kernel_launch(void* const* d_in, const int* in_sizes, int n_in,
                              void* d_out, int out_size, void* d_ws, size_t ws_size,
                              hipStream_t stream) {
    const void* X    = d_in[0];
    const int* eidx  = (const int*)d_in[1];
    const void* eattr= d_in[2];
    const void *WX1 = d_in[3],  *BX1 = d_in[4];
    const void *WE1 = d_in[5],  *BE1 = d_in[6];
    const void *WO1 = d_in[7],  *BO1 = d_in[8];
    const void *WX2 = d_in[9],  *BX2 = d_in[10];
    const void *WE2 = d_in[11], *BE2 = d_in[12];
    const void *WO2 = d_in[13], *BO2 = d_in[14];
    const void *WX3 = d_in[15], *BX3 = d_in[16];
    const void *WE3 = d_in[17], *BE3 = d_in[18];
    const void *WO3 = d_in[19], *BO3 = d_in[20];
    const void *W1  = d_in[21], *B1  = d_in[22];
    const void *W2  = d_in[23], *B2  = d_in[24];

    const int* src = eidx;
    const int* dst = eidx + NEDGES;

    // workspace layout (~180 MB)
    char* w = (char*)d_ws;
    size_t off = 0;
    auto take = [&](size_t bytes) -> void* {
        void* p = w + off;
        off += (bytes + 255) & ~(size_t)255;
        return p;
    };
    int*   row_start = (int*)take((size_t)(NNODES + 1) * 4);
    int*   cursor    = (int*)take((size_t)NNODES * 4);
    int*   part      = (int*)take(4096);
    int*   flag      = (int*)take(256);
    uint2* perm      = (uint2*)take((size_t)NEDGES * 8);     // (src, attr) sorted by dst
    u16*   h2        = (u16*)take((size_t)NNODES * HSTR * 2);
    u16*   h3        = (u16*)take((size_t)NNODES * HSTR * 2);
    u16*   f         = h2;  // layer-3 output (12 MB) reuses h2 (dead by then)
    (void)ws_size; (void)n_in; (void)in_sizes; (void)out_size;

    const int EB = (NEDGES + 255) / 256;
    const int NB = (NNODES + 255) / 256;
    const int TB = (NTRACK + 255) / 256;

    hipMemsetAsync(row_start, 0, (size_t)NNODES * 4, stream);

    k_detect  <<<1,    64,  0, stream>>>((const u16*)BX1, (const u16*)BE1, (const u16*)BO1,
                                         (const u16*)BX2, (const u16*)BE2, (const u16*)B1, flag);
    k_hist    <<<EB,   256, 0, stream>>>(dst, row_start);
    k_reduce  <<<NBLK, 256, 0, stream>>>(row_start, part);
    k_scanpart<<<1,    512, 0, stream>>>(part, row_start);
    k_scandown<<<NBLK, 256, 0, stream>>>(row_start, part, cursor);
    k_scatter <<<EB,   256, 0, stream>>>(src, dst, eattr, cursor, perm, flag);

    k_agg1        <<<NB, 256, 0, stream>>>(row_start, perm, X,
                                           WX1, BX1, WE1, BE1, WO1, BO1, WX2, BX2, h2, flag);
    k_agg<9,true> <<<NB, 256, 0, stream>>>(row_start, perm, h2,
                                           WE2, BE2, WO2, BO2, WX3, BX3, h3, flag);
    k_agg<4,false><<<NB, 256, 0, stream>>>(row_start, perm, h3,
                                           WE3, BE3, WO3, BO3, WO3, BO3, f, flag);
    k_head        <<<TB, 256, 0, stream>>>(f, W1, B1, W2, B2, d_out, flag);
}

// Round 3
// 1672.977 us; speedup vs baseline: 1.4037x; 1.4037x over previous
//
#include <hip/hip_runtime.h>
#include <hip/hip_bf16.h>

// trackletGNN: 3x edge-conv (gather * edge-linear -> scatter-add) + MLP head.
// Sort-by-dst is now a locality-aware two-phase counting sort:
//   k_bhist/k_bscan: 2930-bucket (512 nodes/bucket) histogram + tiny scan
//   k_part:  per-block LDS hist -> one global reservation per (block,bucket)
//            -> block-local run writes (kills the 8x write amplification the
//            old random 8B scatter showed: WRITE_SIZE 751MB for a 96MB array)
//   k_csr:   one block per bucket, IN-PLACE refine to full dst order via LDS,
//            emits row_start. Local node id packed in bits 21..29 of rec.x.
// Aggregation layers unchanged (atomic-free per-node segmented reduction,
// Wo+ReLU+next-Wx fused). Runtime dtype probe (f32 vs bf16) as before.
// Workspace ~174 MB.

#define NNODES 1500000
#define NEDGES 12000000
#define NTRACK 250000
#define HSTR   12          // padded bf16 feature stride (9 used) -> 24B
#define NBUCK  2930        // ceil(NNODES/512)
#define CHUNK  16384       // edges per k_part/k_bhist block
#define PBLK   733         // ceil(NEDGES/CHUNK)
#define CAPB   5120        // LDS slots per bucket in k_csr (mean 4096, +16 sigma)
#define SRCMASK 0x1FFFFFu  // 21 bits

typedef unsigned int   u32;
typedef unsigned short u16;

static __device__ __forceinline__ float b2f(u32 v) {
    union { float f; u32 u; } x; x.u = v << 16; return x.f;
}
static __device__ __forceinline__ u16 f2b(float f) {
    __hip_bfloat16 h = __float2bfloat16(f);
    return *reinterpret_cast<u16*>(&h);
}
static __device__ __forceinline__ float ldw(const void* p, int i, int isf32) {
    return isf32 ? ((const float*)p)[i] : b2f((u32)((const u16*)p)[i]);
}

// ---------------- dtype probe ----------------

__global__ void k_detect(const u16* a, const u16* b, const u16* c,
                         const u16* d, const u16* e, const u16* f,
                         int* flag) {
    if (blockIdx.x == 0 && threadIdx.x == 0) {
        int isf32 = 0;
        const u16* ps[6] = {a, b, c, d, e, f};
        const int  ns[6] = {9, 9, 9, 9, 9, 8};
        for (int k = 0; k < 6; k++)
            for (int i = 0; i < ns[k]; i++) {
                float v = b2f((u32)ps[k][i]);
                if (!(fabsf(v) < 1.0e3f)) isf32 = 1;   // catches NaN/Inf too
            }
        *flag = isf32;
    }
}

// ---------------- phase 1: bucket histogram ----------------

__global__ __launch_bounds__(256) void k_bhist(const int* __restrict__ dst,
                                               int* __restrict__ gh) {
    __shared__ u32 h[NBUCK];
    int t = threadIdx.x;
    for (int b = t; b < NBUCK; b += 256) h[b] = 0;
    __syncthreads();
    int c0 = blockIdx.x * CHUNK;
#pragma unroll 4
    for (int i = 0; i < CHUNK / 256; i++) {
        int e = c0 + i * 256 + t;
        if (e < NEDGES) atomicAdd(&h[((u32)dst[e]) >> 9], 1u);
    }
    __syncthreads();
    for (int b = t; b < NBUCK; b += 256) {
        u32 c = h[b];
        if (c) atomicAdd((u32*)&gh[b], c);
    }
}

__global__ __launch_bounds__(256) void k_bscan(const int* __restrict__ gh,
                                               int* __restrict__ bstart,
                                               int* __restrict__ gcur,
                                               int* __restrict__ row_start) {
    __shared__ u32 sd[256];
    __shared__ u32 carry;
    int t = threadIdx.x;
    if (t == 0) carry = 0;
    __syncthreads();
    for (int c0 = 0; c0 < NBUCK; c0 += 256) {
        int b = c0 + t;
        u32 v = (b < NBUCK) ? (u32)gh[b] : 0;
        sd[t] = v; __syncthreads();
        for (int o = 1; o < 256; o <<= 1) {
            u32 a = (t >= o) ? sd[t - o] : 0;
            __syncthreads();
            sd[t] += a;
            __syncthreads();
        }
        u32 excl = carry + sd[t] - v;
        if (b < NBUCK) { bstart[b] = (int)excl; gcur[b] = (int)excl; }
        __syncthreads();
        if (t == 255) carry += sd[255];
        __syncthreads();
    }
    if (t == 0) { bstart[NBUCK] = NEDGES; row_start[NNODES] = NEDGES; }
}

// ---------------- phase 2: partition into buckets (run-reserved writes) ----

__global__ __launch_bounds__(256) void k_part(const int* __restrict__ src,
                                              const int* __restrict__ dst,
                                              const void* __restrict__ attr,
                                              int* __restrict__ gcur,
                                              uint2* __restrict__ perm,
                                              const int* __restrict__ flag) {
    __shared__ u32 h[NBUCK];
    __shared__ u32 base[NBUCK];
    int isf32 = *flag;
    int t = threadIdx.x;
    for (int b = t; b < NBUCK; b += 256) h[b] = 0;
    __syncthreads();
    int c0 = blockIdx.x * CHUNK;
#pragma unroll 4
    for (int i = 0; i < CHUNK / 256; i++) {
        int e = c0 + i * 256 + t;
        if (e < NEDGES) atomicAdd(&h[((u32)dst[e]) >> 9], 1u);
    }
    __syncthreads();
    for (int b = t; b < NBUCK; b += 256) {
        u32 c = h[b];
        base[b] = c ? (u32)atomicAdd(&gcur[b], (int)c) : 0u;
        h[b] = 0;  // reuse as local cursor
    }
    __syncthreads();
#pragma unroll 4
    for (int i = 0; i < CHUNK / 256; i++) {
        int e = c0 + i * 256 + t;
        if (e < NEDGES) {
            u32 d  = (u32)dst[e];
            u32 bk = d >> 9;
            u32 off = atomicAdd(&h[bk], 1u);
            u32 pos = base[bk] + off;
            u32 ap;
            if (isf32) {
                float2 a = ((const float2*)attr)[e];
                ap = (u32)f2b(a.x) | ((u32)f2b(a.y) << 16);
            } else {
                ap = ((const u32*)attr)[e];
            }
            uint2 rec;
            rec.x = ((u32)src[e]) | ((d & 511u) << 21);
            rec.y = ap;
            perm[pos] = rec;
        }
    }
}

// ---------------- phase 3: in-place per-bucket CSR refine ----------------

__global__ __launch_bounds__(256) void k_csr(const int* __restrict__ bstart,
                                             uint2* __restrict__ perm,
                                             int* __restrict__ row_start) {
    __shared__ uint2 out[CAPB];
    __shared__ u32 h[512], st[512], sd[256];
    int t = threadIdx.x;
    int b = blockIdx.x;
    int r0 = bstart[b], r1 = bstart[b + 1];
    int cnt = r1 - r0;

    for (int i = t; i < 512; i += 256) h[i] = 0;
    __syncthreads();
    for (int i = t; i < cnt; i += 256) {
        uint2 rec = perm[r0 + i];
        atomicAdd(&h[rec.x >> 21], 1u);
    }
    __syncthreads();
    // exclusive scan of h[512], 2 elems/thread
    u32 e0 = h[2 * t], e1 = h[2 * t + 1], s = e0 + e1;
    sd[t] = s; __syncthreads();
    for (int o = 1; o < 256; o <<= 1) {
        u32 a = (t >= o) ? sd[t - o] : 0;
        __syncthreads();
        sd[t] += a;
        __syncthreads();
    }
    u32 excl = sd[t] - s;
    st[2 * t] = excl; st[2 * t + 1] = excl + e0;
    __syncthreads();
    // row_start for this bucket's nodes (coalesced)
    for (int l = t; l < 512; l += 256) {
        int n = b * 512 + l;
        if (n < NNODES) row_start[n] = r0 + (int)st[l];
    }
    // cursors
    for (int l = t; l < 512; l += 256) h[l] = st[l];
    __syncthreads();
    // scatter into LDS (re-read region: L1/L2-hot)
    for (int i = t; i < cnt; i += 256) {
        uint2 rec = perm[r0 + i];
        u32 p = atomicAdd(&h[rec.x >> 21], 1u);
        if (p < CAPB) out[p] = rec;
    }
    __syncthreads();
    // coalesced in-place write-back
    for (int i = t; i < cnt; i += 256) perm[r0 + i] = out[i];
}

// ---- layer 1: gather scalar x, fuse Wx1 + edge-linear + Wo1 + ReLU + Wx2 ----

__global__ __launch_bounds__(256) void k_agg1(
        const int* __restrict__ row_start, const uint2* __restrict__ perm,
        const void* __restrict__ x,
        const void* Wx, const void* bx, const void* We, const void* be,
        const void* Wo, const void* bo, const void* Wxn, const void* bxn,
        u16* __restrict__ hout, const int* __restrict__ flag) {
    __shared__ float sWx[9], sbx[9], sWe[18], sbe[9], sWo[81], sbo[9], sWxn[81], sbxn[9];
    int isf32 = *flag;
    int t = threadIdx.x;
    if (t < 9)  sWx[t]  = ldw(Wx,  t, isf32);
    if (t < 9)  sbx[t]  = ldw(bx,  t, isf32);
    if (t < 18) sWe[t]  = ldw(We,  t, isf32);
    if (t < 9)  sbe[t]  = ldw(be,  t, isf32);
    if (t < 81) sWo[t]  = ldw(Wo,  t, isf32);
    if (t < 9)  sbo[t]  = ldw(bo,  t, isf32);
    if (t < 81) sWxn[t] = ldw(Wxn, t, isf32);
    if (t < 9)  sbxn[t] = ldw(bxn, t, isf32);
    __syncthreads();

    int n = blockIdx.x * 256 + t;
    if (n >= NNODES) return;
    int r0 = row_start[n], r1 = row_start[n + 1];

    float acc[9];
#pragma unroll
    for (int j = 0; j < 9; j++) acc[j] = 0.f;

    auto body = [&](float xs, u32 ap) {
        float a0 = b2f(ap & 0xffffu);
        float a1 = b2f(ap >> 16);
#pragma unroll
        for (int j = 0; j < 9; j++) {
            float e = fmaf(a0, sWe[2 * j], fmaf(a1, sWe[2 * j + 1], sbe[j]));
            float hh = fmaf(xs, sWx[j], sbx[j]);
            acc[j]  = fmaf(hh, e, acc[j]);
        }
    };
    if (isf32) {
        const float* xf = (const float*)x;
        for (int i = r0; i < r1; i++) {
            uint2 rec = perm[i];
            body(xf[rec.x & SRCMASK], rec.y);
        }
    } else {
        const u16* xb = (const u16*)x;
        for (int i = r0; i < r1; i++) {
            uint2 rec = perm[i];
            body(b2f((u32)xb[rec.x & SRCMASK]), rec.y);
        }
    }

    float o[9];
#pragma unroll
    for (int k = 0; k < 9; k++) {
        float v = sbo[k];
#pragma unroll
        for (int j = 0; j < 9; j++) v = fmaf(acc[j], sWo[k * 9 + j], v);
        o[k] = fmaxf(v, 0.f);
    }
    u16 hv[9];
#pragma unroll
    for (int j = 0; j < 9; j++) {
        float v = sbxn[j];
#pragma unroll
        for (int k = 0; k < 9; k++) v = fmaf(o[k], sWxn[j * 9 + k], v);
        hv[j] = f2b(v);
    }
    uint2* op = (uint2*)(hout + (size_t)n * HSTR);
    uint2 q;
    q.x = (u32)hv[0] | ((u32)hv[1] << 16); q.y = (u32)hv[2] | ((u32)hv[3] << 16); op[0] = q;
    q.x = (u32)hv[4] | ((u32)hv[5] << 16); q.y = (u32)hv[6] | ((u32)hv[7] << 16); op[1] = q;
    q.x = (u32)hv[8];                      q.y = 0;                               op[2] = q;
}

// ---------------- layers 2/3: gather 9-vec from bf16 table ----------------

template <int OUTF, bool FUSE_NEXT>
__global__ __launch_bounds__(256) void k_agg(
        const int* __restrict__ row_start, const uint2* __restrict__ perm,
        const u16* __restrict__ hcur,
        const void* We, const void* be, const void* Wo, const void* bo,
        const void* Wxn, const void* bxn,
        u16* __restrict__ hout, const int* __restrict__ flag) {
    __shared__ float sWe[18], sbe[9], sWo[OUTF * 9], sbo[OUTF], sWxn[81], sbxn[9];
    int isf32 = *flag;
    int t = threadIdx.x;
    if (t < 18)       sWe[t] = ldw(We, t, isf32);
    if (t < 9)        sbe[t] = ldw(be, t, isf32);
    if (t < OUTF * 9) sWo[t] = ldw(Wo, t, isf32);
    if (t < OUTF)     sbo[t] = ldw(bo, t, isf32);
    if constexpr (FUSE_NEXT) {
        if (t < 81) sWxn[t] = ldw(Wxn, t, isf32);
        if (t < 9)  sbxn[t] = ldw(bxn, t, isf32);
    }
    __syncthreads();

    int n = blockIdx.x * 256 + t;
    if (n >= NNODES) return;
    int r0 = row_start[n], r1 = row_start[n + 1];

    float acc[9];
#pragma unroll
    for (int j = 0; j < 9; j++) acc[j] = 0.f;

    for (int i = r0; i < r1; i++) {
        uint2 rec = perm[i];
        int   sidx = (int)(rec.x & SRCMASK);
        float a0  = b2f(rec.y & 0xffffu);
        float a1  = b2f(rec.y >> 16);
        const uint2* hp = (const uint2*)(hcur + (size_t)sidx * HSTR);
        uint2 q0 = hp[0], q1 = hp[1], q2 = hp[2];
        float h[9];
        h[0] = b2f(q0.x & 0xffffu); h[1] = b2f(q0.x >> 16);
        h[2] = b2f(q0.y & 0xffffu); h[3] = b2f(q0.y >> 16);
        h[4] = b2f(q1.x & 0xffffu); h[5] = b2f(q1.x >> 16);
        h[6] = b2f(q1.y & 0xffffu); h[7] = b2f(q1.y >> 16);
        h[8] = b2f(q2.x & 0xffffu);
#pragma unroll
        for (int j = 0; j < 9; j++) {
            float e = fmaf(a0, sWe[2 * j], fmaf(a1, sWe[2 * j + 1], sbe[j]));
            acc[j]  = fmaf(h[j], e, acc[j]);
        }
    }

    float o[OUTF];
#pragma unroll
    for (int k = 0; k < OUTF; k++) {
        float v = sbo[k];
#pragma unroll
        for (int j = 0; j < 9; j++) v = fmaf(acc[j], sWo[k * 9 + j], v);
        o[k] = fmaxf(v, 0.f);
    }

    if constexpr (FUSE_NEXT) {
        u16 hv[9];
#pragma unroll
        for (int j = 0; j < 9; j++) {
            float v = sbxn[j];
#pragma unroll
            for (int k = 0; k < OUTF; k++) v = fmaf(o[k], sWxn[j * 9 + k], v);
            hv[j] = f2b(v);
        }
        uint2* op = (uint2*)(hout + (size_t)n * HSTR);
        uint2 q;
        q.x = (u32)hv[0] | ((u32)hv[1] << 16); q.y = (u32)hv[2] | ((u32)hv[3] << 16); op[0] = q;
        q.x = (u32)hv[4] | ((u32)hv[5] << 16); q.y = (u32)hv[6] | ((u32)hv[7] << 16); op[1] = q;
        q.x = (u32)hv[8];                      q.y = 0;                               op[2] = q;
    } else {
        uint2 q;
        q.x = (u32)f2b(o[0]) | ((u32)f2b(o[1]) << 16);
        q.y = (u32)f2b(o[2]) | ((u32)f2b(o[3]) << 16);
        ((uint2*)(hout + (size_t)n * 4))[0] = q;
    }
}

// ---------------- head MLP + log_softmax ----------------

__global__ __launch_bounds__(256) void k_head(
        const u16* __restrict__ f,
        const void* W1, const void* b1, const void* W2, const void* b2,
        void* __restrict__ out, const int* __restrict__ flag) {
    __shared__ float sW1[192], sb1[8], sW2[32], sb2[4];
    int isf32 = *flag;
    int t = threadIdx.x;
    if (t < 192) sW1[t] = ldw(W1, t, isf32);
    if (t < 8)   sb1[t] = ldw(b1, t, isf32);
    if (t < 32)  sW2[t] = ldw(W2, t, isf32);
    if (t < 4)   sb2[t] = ldw(b2, t, isf32);
    __syncthreads();

    int tr = blockIdx.x * 256 + t;
    if (tr >= NTRACK) return;

    const uint4* fp = (const uint4*)(f + (size_t)tr * 24);
    uint4 A = fp[0], B = fp[1], C = fp[2];
    u32 w[12] = {A.x, A.y, A.z, A.w, B.x, B.y, B.z, B.w, C.x, C.y, C.z, C.w};
    float in[24];
#pragma unroll
    for (int i = 0; i < 12; i++) {
        in[2 * i]     = b2f(w[i] & 0xffffu);
        in[2 * i + 1] = b2f(w[i] >> 16);
    }

    float z1[8];
#pragma unroll
    for (int o = 0; o < 8; o++) {
        float v = sb1[o];
#pragma unroll
        for (int i = 0; i < 24; i++) v = fmaf(in[i], sW1[o * 24 + i], v);
        z1[o] = fmaxf(v, 0.f);
    }
    float z2[4];
#pragma unroll
    for (int c = 0; c < 4; c++) {
        float v = sb2[c];
#pragma unroll
        for (int o = 0; o < 8; o++) v = fmaf(z1[o], sW2[c * 8 + o], v);
        z2[c] = v;
    }
    float m = fmaxf(fmaxf(z2[0], z2[1]), fmaxf(z2[2], z2[3]));
    float s = 0.f;
#pragma unroll
    for (int c = 0; c < 4; c++) s += expf(z2[c] - m);
    float l = logf(s) + m;

    if (isf32) {
        float4 q; q.x = z2[0] - l; q.y = z2[1] - l; q.z = z2[2] - l; q.w = z2[3] - l;
        ((float4*)((float*)out + (size_t)tr * 4))[0] = q;
    } else {
        uint2 q;
        q.x = (u32)f2b(z2[0] - l) | ((u32)f2b(z2[1] - l) << 16);
        q.y = (u32)f2b(z2[2] - l) | ((u32)f2b(z2[3] - l) << 16);
        ((uint2*)((u16*)out + (size_t)tr * 4))[0] = q;
    }
}

// ---------------- host ----------------

extern "C" void kernel_launch(void* const* d_in, const int* in_sizes, int n_in,
                              void* d_out, int out_size, void* d_ws, size_t ws_size,
                              hipStream_t stream) {
    const void* X    = d_in[0];
    const int* eidx  = (const int*)d_in[1];
    const void* eattr= d_in[2];
    const void *WX1 = d_in[3],  *BX1 = d_in[4];
    const void *WE1 = d_in[5],  *BE1 = d_in[6];
    const void *WO1 = d_in[7],  *BO1 = d_in[8];
    const void *WX2 = d_in[9],  *BX2 = d_in[10];
    const void *WE2 = d_in[11], *BE2 = d_in[12];
    const void *WO2 = d_in[13], *BO2 = d_in[14];
    const void *WX3 = d_in[15], *BX3 = d_in[16];
    const void *WE3 = d_in[17], *BE3 = d_in[18];
    const void *WO3 = d_in[19], *BO3 = d_in[20];
    const void *W1  = d_in[21], *B1  = d_in[22];
    const void *W2  = d_in[23], *B2  = d_in[24];

    const int* src = eidx;
    const int* dst = eidx + NEDGES;

    // workspace layout (~174 MB)
    char* w = (char*)d_ws;
    size_t off = 0;
    auto take = [&](size_t bytes) -> void* {
        void* p = w + off;
        off += (bytes + 255) & ~(size_t)255;
        return p;
    };
    int*   row_start = (int*)take((size_t)(NNODES + 1) * 4);   // 6 MB
    int*   flag      = (int*)take(256);
    int*   gh        = (int*)take((size_t)NBUCK * 4);          // bucket hist
    int*   bstart    = (int*)take((size_t)(NBUCK + 1) * 4);    // bucket starts
    int*   gcur      = (int*)take((size_t)NBUCK * 4);          // bucket cursors
    uint2* perm      = (uint2*)take((size_t)NEDGES * 8);       // 96 MB
    u16*   h2        = (u16*)take((size_t)NNODES * HSTR * 2);  // 36 MB
    u16*   h3        = (u16*)take((size_t)NNODES * HSTR * 2);  // 36 MB
    u16*   f         = h2;  // layer-3 output (12 MB) reuses h2 (dead by then)
    (void)ws_size; (void)n_in; (void)in_sizes; (void)out_size;

    const int NB = (NNODES + 255) / 256;
    const int TB = (NTRACK + 255) / 256;

    hipMemsetAsync(gh, 0, (size_t)NBUCK * 4, stream);

    k_detect <<<1,     64,  0, stream>>>((const u16*)BX1, (const u16*)BE1, (const u16*)BO1,
                                         (const u16*)BX2, (const u16*)BE2, (const u16*)B1, flag);
    k_bhist  <<<PBLK,  256, 0, stream>>>(dst, gh);
    k_bscan  <<<1,     256, 0, stream>>>(gh, bstart, gcur, row_start);
    k_part   <<<PBLK,  256, 0, stream>>>(src, dst, eattr, gcur, perm, flag);
    k_csr    <<<NBUCK, 256, 0, stream>>>(bstart, perm, row_start);

    k_agg1        <<<NB, 256, 0, stream>>>(row_start, perm, X,
                                           WX1, BX1, WE1, BE1, WO1, BO1, WX2, BX2, h2, flag);
    k_agg<9,true> <<<NB, 256, 0, stream>>>(row_start, perm, h2,
                                           WE2, BE2, WO2, BO2, WX3, BX3, h3, flag);
    k_agg<4,false><<<NB, 256, 0, stream>>>(row_start, perm, h3,
                                           WE3, BE3, WO3, BO3, WO3, BO3, f, flag);
    k_head        <<<TB, 256, 0, stream>>>(f, W1, B1, W2, B2, d_out, flag);
}